// Round 6
// baseline (290.386 us; speedup 1.0000x reference)
//
#include <hip/hip_runtime.h>

#define N_ATOMS 4096
#define D_DESC 352
#define NBLK16 256   // max 16-atom blocks per type
typedef unsigned long long ull;

// transposed descriptor/activation layout: [type][blk16][feature][q], q = p&15
__device__ __forceinline__ size_t dt_idx(int t, int p, int dd) {
    return (((size_t)t * NBLK16 + (p >> 4)) * D_DESC + dd) * 16 + (p & 15);
}

__device__ __forceinline__ float wrapr(float d, float box, float rbox) {
    return d - box * rintf(d * rbox);
}

__global__ __launch_bounds__(256) void build_lists_kernel(
    const int* __restrict__ types, int* __restrict__ cnt,
    int* __restrict__ lists, int* __restrict__ pos)
{
    int i = blockIdx.x * 256 + threadIdx.x;
    if (i < N_ATOMS) {
        int t = types[i];
        int p = atomicAdd(&cnt[t], 1);
        lists[t * N_ATOMS + p] = i;
        pos[i] = p;
    }
}

// packed[t][m] = (x, y, z, bits(j)) in list order -> coalesced select loads
__global__ __launch_bounds__(256) void pack_kernel(
    const float* __restrict__ xyz, const int* __restrict__ cnt,
    const int* __restrict__ lists, float4* __restrict__ packed)
{
    int idx = blockIdx.x * 256 + threadIdx.x;   // [0, 2*4096)
    int t = idx >> 12, m = idx & 4095;
    if (m < cnt[t]) {
        int j = lists[t * N_ATOMS + m];
        packed[idx] = make_float4(xyz[3*j+0], xyz[3*j+1], xyz[3*j+2],
                                  __uint_as_float((unsigned)j));
    }
}

// One block per (atom, type): threshold filter (count in [128,256]) then
// 256-wide bitonic sort on 43-bit keys -> exact sorted top-128.
__global__ __launch_bounds__(256) void select_kernel(
    const float* __restrict__ xyz, const float* __restrict__ box,
    const int* __restrict__ cnt, const float4* __restrict__ packed,
    const int* __restrict__ types, const int* __restrict__ pos,
    float* __restrict__ descT, float* __restrict__ aX, float* __restrict__ aD,
    float* __restrict__ lfD, int* __restrict__ lfJ)
{
    __shared__ int part[2][4];
    __shared__ ull cand[512];
    __shared__ int cpos;

    const int i   = blockIdx.x >> 1;
    const int t   = blockIdx.x & 1;
    const int tid = threadIdx.x;
    const int n   = cnt[t];
    const float bx = box[0], by = box[1], bz = box[2];
    const float rbx = 1.0f/bx, rby = 1.0f/by, rbz = 1.0f/bz;
    const float xi = xyz[3*i+0], yi = xyz[3*i+1], zi = xyz[3*i+2];
    const unsigned ibits = (unsigned)i;
    const float4* pk = packed + t * N_ATOMS;

    // --- coalesced distance pass ---
    float d2r[16];
    #pragma unroll
    for (int c = 0; c < 16; ++c) {
        d2r[c] = __builtin_inff();
        int m = tid + (c << 8);
        if (m < n) {
            float4 p = pk[m];
            if (__float_as_uint(p.w) != ibits) {
                float dx = wrapr(xi - p.x, bx, rbx);
                float dy = wrapr(yi - p.y, by, rby);
                float dz = wrapr(zi - p.z, bz, rbz);
                d2r[c] = dx*dx + dy*dy + dz*dz;
            }
        }
    }

    if (tid == 0) cpos = 0;

    // --- threshold with count in [128, 256]; interpolated update ---
    float T = __powf(42.0f * bx * by * bz / (float)n, 0.6666667f);
    int tot = 0;
    for (int it = 0; it < 24; ++it) {
        int lc = 0;
        #pragma unroll
        for (int c = 0; c < 16; ++c) lc += (d2r[c] < T) ? 1 : 0;
        #pragma unroll
        for (int off = 32; off > 0; off >>= 1) lc += __shfl_xor(lc, off);
        if ((tid & 63) == 0) part[it & 1][tid >> 6] = lc;
        __syncthreads();
        tot = part[it & 1][0] + part[it & 1][1] + part[it & 1][2] + part[it & 1][3];
        if (tot >= 128 && tot <= 256) break;
        float f = __powf(176.0f / (float)max(tot, 1), 0.6666667f);
        T *= fminf(4.0f, fmaxf(0.25f, f));
    }

    // --- collect keys below T (exact superset of top-128) ---
    #pragma unroll
    for (int c = 0; c < 16; ++c) {
        if (d2r[c] < T) {
            int m = tid + (c << 8);
            unsigned j = __float_as_uint(pk[m].w);
            ull key = ((ull)__float_as_uint(d2r[c]) << 12) | j;
            int p = atomicAdd(&cpos, 1);
            if (p < 512) cand[p] = key;
        }
    }
    const int count  = (tot <= 512) ? tot : 512;
    const int sort_n = (count <= 256) ? 256 : 512;
    for (int m = tid + count; m < sort_n; m += 256) cand[m] = ~0ull;
    __syncthreads();

    // --- bitonic sort ---
    for (int kk = 2; kk <= sort_n; kk <<= 1) {
        for (int jj = kk >> 1; jj > 0; jj >>= 1) {
            for (int m = tid; m < sort_n; m += 256) {
                int p = m ^ jj;
                if (p > m) {
                    ull a = cand[m], b = cand[p];
                    bool asc = ((m & kk) == 0);
                    if (asc ? (a > b) : (a < b)) { cand[m] = b; cand[p] = a; }
                }
            }
            __syncthreads();
        }
    }

    // --- outputs ---
    if (tid < 128) {
        const int ti = types[i];
        const int pi = pos[i];
        ull key = cand[tid];
        int j   = (int)(key & 0xFFF);
        float d2 = __uint_as_float((unsigned)(key >> 12));
        float dist = sqrtf(d2);
        descT[dt_idx(ti, pi, t * 128 + tid)] = 1.0f / (dist + 1e-16f);
        if (tid < 16) {
            float dx = wrapr(xi - xyz[3*j+0], bx, rbx);
            float dy = wrapr(yi - xyz[3*j+1], by, rby);
            float dz = wrapr(zi - xyz[3*j+2], bz, rbz);
            int s = i * 32 + t * 16 + tid;
            aX[3*s+0] = dx; aX[3*s+1] = dy; aX[3*s+2] = dz;
            aD[s] = dist;
        }
        if (tid < 2) {
            lfD[i * 4 + t * 2 + tid] = dist;
            lfJ[i * 4 + t * 2 + tid] = j;
        }
    }
}

// One block (64 threads) per atom: local frame + rotated angular features.
__global__ __launch_bounds__(64) void finalize_kernel(
    const float* __restrict__ xyz, const float* __restrict__ box,
    const int* __restrict__ types, const int* __restrict__ pos,
    const float* __restrict__ aX, const float* __restrict__ aD,
    const float* __restrict__ lfD, const int* __restrict__ lfJ,
    float* __restrict__ descT)
{
    __shared__ float Amat[9];
    const int i   = blockIdx.x;
    const int tid = threadIdx.x;

    if (tid == 0) {
        const float bx = box[0], by = box[1], bz = box[2];
        const float rbx = 1.0f/bx, rby = 1.0f/by, rbz = 1.0f/bz;
        const float xi = xyz[3*i+0], yi = xyz[3*i+1], zi = xyz[3*i+2];
        float cd[4]; int cj[4];
        #pragma unroll
        for (int c = 0; c < 4; ++c) { cd[c] = lfD[i*4+c]; cj[c] = lfJ[i*4+c]; }
        int i0 = 0; float b0 = cd[0];
        for (int c = 1; c < 4; ++c) if (cd[c] < b0) { b0 = cd[c]; i0 = c; }
        int i1 = -1; float b1v = 3.4e38f;
        for (int c = 0; c < 4; ++c) { if (c == i0) continue; if (cd[c] < b1v) { b1v = cd[c]; i1 = c; } }

        int ja = cj[i0], jb = cj[i1];
        float da = cd[i0], db = cd[i1];
        float r0x = wrapr(xi - xyz[3*ja+0], bx, rbx) / (da + 1e-16f);
        float r0y = wrapr(yi - xyz[3*ja+1], by, rby) / (da + 1e-16f);
        float r0z = wrapr(zi - xyz[3*ja+2], bz, rbz) / (da + 1e-16f);
        float r1x = wrapr(xi - xyz[3*jb+0], bx, rbx) / (db + 1e-16f);
        float r1y = wrapr(yi - xyz[3*jb+1], by, rby) / (db + 1e-16f);
        float r1z = wrapr(zi - xyz[3*jb+2], bz, rbz) / (db + 1e-16f);
        float dot = r0x*r1x + r0y*r1y + r0z*r1z;
        float v2x = r1x - dot*r0x, v2y = r1y - dot*r0y, v2z = r1z - dot*r0z;
        float n2 = sqrtf(v2x*v2x + v2y*v2y + v2z*v2z);
        v2x /= n2; v2y /= n2; v2z /= n2;
        float v3x = r0y*r1z - r0z*r1y;
        float v3y = r0z*r1x - r0x*r1z;
        float v3z = r0x*r1y - r0y*r1x;
        float n3 = sqrtf(v3x*v3x + v3y*v3y + v3z*v3z);
        v3x /= n3; v3y /= n3; v3z /= n3;
        Amat[0]=r0x; Amat[1]=r0y; Amat[2]=r0z;
        Amat[3]=v2x; Amat[4]=v2y; Amat[5]=v2z;
        Amat[6]=v3x; Amat[7]=v3y; Amat[8]=v3z;
    }
    __syncthreads();

    if (tid < 32) {
        const int ti = types[i];
        const int pi = pos[i];
        int s = i * 32 + tid;
        float d  = aD[s];
        float dn = d + 1e-16f;
        float ax = aX[3*s+0] / dn;
        float ay = aX[3*s+1] / dn;
        float az = aX[3*s+2] / dn;
        float o0 = (Amat[0]*ax + Amat[1]*ay + Amat[2]*az) / dn;
        float o1 = (Amat[3]*ax + Amat[4]*ay + Amat[5]*az) / dn;
        float o2 = (Amat[6]*ax + Amat[7]*ay + Amat[8]*az) / dn;
        descT[dt_idx(ti, pi, 256 + 3*tid + 0)] = o0;
        descT[dt_idx(ti, pi, 256 + 3*tid + 1)] = o1;
        descT[dt_idx(ti, pi, 256 + 3*tid + 2)] = o2;
    }
}

// One layer: block = (type, 16-atom blk), thread = output neuron.
// Wave-uniform activation loads (scalar pipe); weight loads coalesced,
// reused across 16 atoms.
template<int K>
__global__ __launch_bounds__(256) void layer_kernel(
    const int* __restrict__ cnt,
    const float* __restrict__ actT,   // [2][NBLK16][K][16]
    const float* __restrict__ W,      // [2][K][256]
    const float* __restrict__ B,      // [2][256]
    float* __restrict__ outT)         // [2][NBLK16][256][16]
{
    const int t   = blockIdx.y;
    const int blk = blockIdx.x;
    const int o   = threadIdx.x;
    if (blk * 16 >= cnt[t]) return;

    const float* a = actT + ((size_t)t * NBLK16 + blk) * ((size_t)K * 16);
    const float* w = W + (size_t)t * K * 256 + o;

    float acc[16];
    const float bias = B[t * 256 + o];
    #pragma unroll
    for (int q = 0; q < 16; ++q) acc[q] = bias;

    #pragma unroll 2
    for (int d = 0; d < K; ++d) {
        float wv = w[(size_t)d * 256];
        const float4* a4 = (const float4*)(a + (size_t)d * 16);
        float4 a0 = a4[0], a1 = a4[1], a2 = a4[2], a3 = a4[3];
        acc[ 0] = fmaf(a0.x, wv, acc[ 0]);
        acc[ 1] = fmaf(a0.y, wv, acc[ 1]);
        acc[ 2] = fmaf(a0.z, wv, acc[ 2]);
        acc[ 3] = fmaf(a0.w, wv, acc[ 3]);
        acc[ 4] = fmaf(a1.x, wv, acc[ 4]);
        acc[ 5] = fmaf(a1.y, wv, acc[ 5]);
        acc[ 6] = fmaf(a1.z, wv, acc[ 6]);
        acc[ 7] = fmaf(a1.w, wv, acc[ 7]);
        acc[ 8] = fmaf(a2.x, wv, acc[ 8]);
        acc[ 9] = fmaf(a2.y, wv, acc[ 9]);
        acc[10] = fmaf(a2.z, wv, acc[10]);
        acc[11] = fmaf(a2.w, wv, acc[11]);
        acc[12] = fmaf(a3.x, wv, acc[12]);
        acc[13] = fmaf(a3.y, wv, acc[13]);
        acc[14] = fmaf(a3.z, wv, acc[14]);
        acc[15] = fmaf(a3.w, wv, acc[15]);
    }

    float* op = outT + (((size_t)t * NBLK16 + blk) * 256 + o) * 16;
    #pragma unroll
    for (int q = 0; q < 16; ++q) op[q] = tanhf(acc[q]);
}

// Layer 3 + output layer + energy sum, fused.
__global__ __launch_bounds__(256) void layer3_energy_kernel(
    const int* __restrict__ cnt,
    const float* __restrict__ actT,   // h2T
    const float* __restrict__ W,      // w3
    const float* __restrict__ B,      // b3
    const float* __restrict__ w4, const float* __restrict__ b4,
    float* __restrict__ out)
{
    __shared__ float red[256];
    const int t   = blockIdx.y;
    const int blk = blockIdx.x;
    const int o   = threadIdx.x;
    const int n   = cnt[t];
    if (blk * 16 >= n) return;
    const int nv = min(16, n - blk * 16);

    const float* a = actT + ((size_t)t * NBLK16 + blk) * (256 * 16);
    const float* w = W + (size_t)t * 256 * 256 + o;

    float acc[16];
    const float bias = B[t * 256 + o];
    #pragma unroll
    for (int q = 0; q < 16; ++q) acc[q] = bias;

    #pragma unroll 2
    for (int d = 0; d < 256; ++d) {
        float wv = w[(size_t)d * 256];
        const float4* a4 = (const float4*)(a + (size_t)d * 16);
        float4 a0 = a4[0], a1 = a4[1], a2 = a4[2], a3 = a4[3];
        acc[ 0] = fmaf(a0.x, wv, acc[ 0]);
        acc[ 1] = fmaf(a0.y, wv, acc[ 1]);
        acc[ 2] = fmaf(a0.z, wv, acc[ 2]);
        acc[ 3] = fmaf(a0.w, wv, acc[ 3]);
        acc[ 4] = fmaf(a1.x, wv, acc[ 4]);
        acc[ 5] = fmaf(a1.y, wv, acc[ 5]);
        acc[ 6] = fmaf(a1.z, wv, acc[ 6]);
        acc[ 7] = fmaf(a1.w, wv, acc[ 7]);
        acc[ 8] = fmaf(a2.x, wv, acc[ 8]);
        acc[ 9] = fmaf(a2.y, wv, acc[ 9]);
        acc[10] = fmaf(a2.z, wv, acc[10]);
        acc[11] = fmaf(a2.w, wv, acc[11]);
        acc[12] = fmaf(a3.x, wv, acc[12]);
        acc[13] = fmaf(a3.y, wv, acc[13]);
        acc[14] = fmaf(a3.z, wv, acc[14]);
        acc[15] = fmaf(a3.w, wv, acc[15]);
    }

    const float w4v = w4[t * 256 + o];
    float s = 0.0f;
    for (int q = 0; q < nv; ++q) s += tanhf(acc[q]) * w4v;
    red[o] = s;
    __syncthreads();
    for (int w2 = 128; w2 > 0; w2 >>= 1) {
        if (o < w2) red[o] += red[o + w2];
        __syncthreads();
    }
    if (o == 0) atomicAdd(out, red[0] + (float)nv * b4[t]);
}

extern "C" void kernel_launch(void* const* d_in, const int* in_sizes, int n_in,
                              void* d_out, int out_size, void* d_ws, size_t ws_size,
                              hipStream_t stream) {
    const float* xyz   = (const float*)d_in[0];
    const float* box   = (const float*)d_in[1];
    const int*   types = (const int*)  d_in[2];
    const float* w1 = (const float*)d_in[3];
    const float* b1 = (const float*)d_in[4];
    const float* w2 = (const float*)d_in[5];
    const float* b2 = (const float*)d_in[6];
    const float* w3 = (const float*)d_in[7];
    const float* b3 = (const float*)d_in[8];
    const float* w4 = (const float*)d_in[9];
    const float* b4 = (const float*)d_in[10];
    float* out = (float*)d_out;

    // workspace layout (4B units; packed kept 16B-aligned)
    float* p = (float*)d_ws;
    int*    cnt    = (int*)p;          p += 16;
    int*    pos    = (int*)p;          p += N_ATOMS;
    int*    lists  = (int*)p;          p += 2 * N_ATOMS;
    float4* packed = (float4*)p;       p += 2 * N_ATOMS * 4;
    float*  lfD    = p;                p += 4 * N_ATOMS;
    int*    lfJ    = (int*)p;          p += 4 * N_ATOMS;
    float*  aX     = p;                p += 96 * N_ATOMS;
    float*  aD     = p;                p += 32 * N_ATOMS;
    float*  descT  = p;                p += (size_t)2 * NBLK16 * D_DESC * 16;
    float*  h1T    = p;                p += (size_t)2 * NBLK16 * 256 * 16;
    float*  h2T    = p;                p += (size_t)2 * NBLK16 * 256 * 16;

    hipMemsetAsync(d_out, 0, sizeof(float), stream);
    hipMemsetAsync(d_ws, 0, 2 * sizeof(int), stream);

    build_lists_kernel<<<N_ATOMS / 256, 256, 0, stream>>>(types, cnt, lists, pos);
    pack_kernel<<<2 * N_ATOMS / 256, 256, 0, stream>>>(xyz, cnt, lists, packed);
    select_kernel<<<2 * N_ATOMS, 256, 0, stream>>>(xyz, box, cnt, packed, types, pos,
                                                   descT, aX, aD, lfD, lfJ);
    finalize_kernel<<<N_ATOMS, 64, 0, stream>>>(xyz, box, types, pos,
                                                aX, aD, lfD, lfJ, descT);
    dim3 g(NBLK16, 2);
    layer_kernel<D_DESC><<<g, 256, 0, stream>>>(cnt, descT, w1, b1, h1T);
    layer_kernel<256><<<g, 256, 0, stream>>>(cnt, h1T, w2, b2, h2T);
    layer3_energy_kernel<<<g, 256, 0, stream>>>(cnt, h2T, w3, b3, w4, b4, out);
}

// Round 7
// 210.377 us; speedup vs baseline: 1.3803x; 1.3803x over previous
//
#include <hip/hip_runtime.h>

#define N_ATOMS 4096
#define D_DESC 352
#define NBLK 512   // 8-atom blocks per type
typedef unsigned long long ull;

// transposed descriptor/activation layout: [type][blk8][feature][q], q = p&7
__device__ __forceinline__ size_t dt_idx(int t, int p, int dd) {
    return (((size_t)t * NBLK + (p >> 3)) * D_DESC + dd) * 8 + (p & 7);
}

__device__ __forceinline__ float wrapr(float d, float box, float rbox) {
    return d - box * rintf(d * rbox);
}

__global__ __launch_bounds__(256) void build_lists_kernel(
    const int* __restrict__ types, int* __restrict__ cnt,
    int* __restrict__ lists, int* __restrict__ pos)
{
    int i = blockIdx.x * 256 + threadIdx.x;
    if (i < N_ATOMS) {
        int t = types[i];
        int p = atomicAdd(&cnt[t], 1);
        lists[t * N_ATOMS + p] = i;
        pos[i] = p;
    }
}

// packed[t][m] = (x, y, z, bits(j)) in list order -> coalesced select loads
__global__ __launch_bounds__(256) void pack_kernel(
    const float* __restrict__ xyz, const int* __restrict__ cnt,
    const int* __restrict__ lists, float4* __restrict__ packed)
{
    int idx = blockIdx.x * 256 + threadIdx.x;   // [0, 2*4096)
    int t = idx >> 12, m = idx & 4095;
    if (m < cnt[t]) {
        int j = lists[t * N_ATOMS + m];
        packed[idx] = make_float4(xyz[3*j+0], xyz[3*j+1], xyz[3*j+2],
                                  __uint_as_float((unsigned)j));
    }
}

// One block per (atom, type): threshold filter (count in [128,256]), then
// RANK-based exact placement (no bitonic sort): each candidate's output slot
// is its rank among collected 43-bit keys (d2bits<<12 | j), unique & exact.
__global__ __launch_bounds__(256) void select_kernel(
    const float* __restrict__ xyz, const float* __restrict__ box,
    const int* __restrict__ cnt, const float4* __restrict__ packed,
    const int* __restrict__ types, const int* __restrict__ pos,
    float* __restrict__ descT, float* __restrict__ aX, float* __restrict__ aD,
    float* __restrict__ lfD, int* __restrict__ lfJ)
{
    __shared__ int part[2][4];
    __shared__ ull cand[512];
    __shared__ int cpos;

    const int i   = blockIdx.x >> 1;
    const int t   = blockIdx.x & 1;
    const int tid = threadIdx.x;
    const int n   = cnt[t];
    const float bx = box[0], by = box[1], bz = box[2];
    const float rbx = 1.0f/bx, rby = 1.0f/by, rbz = 1.0f/bz;
    const float xi = xyz[3*i+0], yi = xyz[3*i+1], zi = xyz[3*i+2];
    const unsigned ibits = (unsigned)i;
    const float4* pk = packed + t * N_ATOMS;

    // --- coalesced distance pass ---
    float d2r[16];
    #pragma unroll
    for (int c = 0; c < 16; ++c) {
        d2r[c] = __builtin_inff();
        int m = tid + (c << 8);
        if (m < n) {
            float4 p = pk[m];
            if (__float_as_uint(p.w) != ibits) {
                float dx = wrapr(xi - p.x, bx, rbx);
                float dy = wrapr(yi - p.y, by, rby);
                float dz = wrapr(zi - p.z, bz, rbz);
                d2r[c] = dx*dx + dy*dy + dz*dz;
            }
        }
    }

    if (tid == 0) cpos = 0;

    // --- threshold with count in [128, 256]; interpolated update ---
    float T = __powf(42.0f * bx * by * bz / (float)n, 0.6666667f);
    int tot = 0;
    for (int it = 0; it < 24; ++it) {
        int lc = 0;
        #pragma unroll
        for (int c = 0; c < 16; ++c) lc += (d2r[c] < T) ? 1 : 0;
        #pragma unroll
        for (int off = 32; off > 0; off >>= 1) lc += __shfl_xor(lc, off);
        if ((tid & 63) == 0) part[it & 1][tid >> 6] = lc;
        __syncthreads();
        tot = part[it & 1][0] + part[it & 1][1] + part[it & 1][2] + part[it & 1][3];
        if (tot >= 128 && tot <= 256) break;
        float f = __powf(176.0f / (float)max(tot, 1), 0.6666667f);
        T *= fminf(4.0f, fmaxf(0.25f, f));
    }

    // --- collect keys below T (exact superset of top-128) ---
    #pragma unroll
    for (int c = 0; c < 16; ++c) {
        if (d2r[c] < T) {
            int m = tid + (c << 8);
            unsigned j = __float_as_uint(pk[m].w);
            ull key = ((ull)__float_as_uint(d2r[c]) << 12) | j;
            int p = atomicAdd(&cpos, 1);
            if (p < 512) cand[p] = key;
        }
    }
    __syncthreads();
    const int count = min(cpos, 512);

    // --- rank-based placement: slot = #{keys < mykey}, exact sorted order ---
    const int ti = types[i];
    const int pi = pos[i];
    for (int m = tid; m < count; m += 256) {
        ull mykey = cand[m];
        int r = 0;
        #pragma unroll 4
        for (int k2 = 0; k2 < count; ++k2) r += (cand[k2] < mykey) ? 1 : 0;
        if (r < 128) {
            int j = (int)(mykey & 0xFFF);
            float d2 = __uint_as_float((unsigned)(mykey >> 12));
            float dist = sqrtf(d2);
            descT[dt_idx(ti, pi, t * 128 + r)] = 1.0f / (dist + 1e-16f);
            if (r < 16) {
                float dx = wrapr(xi - xyz[3*j+0], bx, rbx);
                float dy = wrapr(yi - xyz[3*j+1], by, rby);
                float dz = wrapr(zi - xyz[3*j+2], bz, rbz);
                int s = i * 32 + t * 16 + r;
                aX[3*s+0] = dx; aX[3*s+1] = dy; aX[3*s+2] = dz;
                aD[s] = dist;
            }
            if (r < 2) {
                lfD[i * 4 + t * 2 + r] = dist;
                lfJ[i * 4 + t * 2 + r] = j;
            }
        }
    }
}

// One block (64 threads) per atom: local frame + rotated angular features.
__global__ __launch_bounds__(64) void finalize_kernel(
    const float* __restrict__ xyz, const float* __restrict__ box,
    const int* __restrict__ types, const int* __restrict__ pos,
    const float* __restrict__ aX, const float* __restrict__ aD,
    const float* __restrict__ lfD, const int* __restrict__ lfJ,
    float* __restrict__ descT)
{
    __shared__ float Amat[9];
    const int i   = blockIdx.x;
    const int tid = threadIdx.x;

    if (tid == 0) {
        const float bx = box[0], by = box[1], bz = box[2];
        const float rbx = 1.0f/bx, rby = 1.0f/by, rbz = 1.0f/bz;
        const float xi = xyz[3*i+0], yi = xyz[3*i+1], zi = xyz[3*i+2];
        float cd[4]; int cj[4];
        #pragma unroll
        for (int c = 0; c < 4; ++c) { cd[c] = lfD[i*4+c]; cj[c] = lfJ[i*4+c]; }
        int i0 = 0; float b0 = cd[0];
        for (int c = 1; c < 4; ++c) if (cd[c] < b0) { b0 = cd[c]; i0 = c; }
        int i1 = -1; float b1v = 3.4e38f;
        for (int c = 0; c < 4; ++c) { if (c == i0) continue; if (cd[c] < b1v) { b1v = cd[c]; i1 = c; } }

        int ja = cj[i0], jb = cj[i1];
        float da = cd[i0], db = cd[i1];
        float r0x = wrapr(xi - xyz[3*ja+0], bx, rbx) / (da + 1e-16f);
        float r0y = wrapr(yi - xyz[3*ja+1], by, rby) / (da + 1e-16f);
        float r0z = wrapr(zi - xyz[3*ja+2], bz, rbz) / (da + 1e-16f);
        float r1x = wrapr(xi - xyz[3*jb+0], bx, rbx) / (db + 1e-16f);
        float r1y = wrapr(yi - xyz[3*jb+1], by, rby) / (db + 1e-16f);
        float r1z = wrapr(zi - xyz[3*jb+2], bz, rbz) / (db + 1e-16f);
        float dot = r0x*r1x + r0y*r1y + r0z*r1z;
        float v2x = r1x - dot*r0x, v2y = r1y - dot*r0y, v2z = r1z - dot*r0z;
        float n2 = sqrtf(v2x*v2x + v2y*v2y + v2z*v2z);
        v2x /= n2; v2y /= n2; v2z /= n2;
        float v3x = r0y*r1z - r0z*r1y;
        float v3y = r0z*r1x - r0x*r1z;
        float v3z = r0x*r1y - r0y*r1x;
        float n3 = sqrtf(v3x*v3x + v3y*v3y + v3z*v3z);
        v3x /= n3; v3y /= n3; v3z /= n3;
        Amat[0]=r0x; Amat[1]=r0y; Amat[2]=r0z;
        Amat[3]=v2x; Amat[4]=v2y; Amat[5]=v2z;
        Amat[6]=v3x; Amat[7]=v3y; Amat[8]=v3z;
    }
    __syncthreads();

    if (tid < 32) {
        const int ti = types[i];
        const int pi = pos[i];
        int s = i * 32 + tid;
        float d  = aD[s];
        float dn = d + 1e-16f;
        float ax = aX[3*s+0] / dn;
        float ay = aX[3*s+1] / dn;
        float az = aX[3*s+2] / dn;
        float o0 = (Amat[0]*ax + Amat[1]*ay + Amat[2]*az) / dn;
        float o1 = (Amat[3]*ax + Amat[4]*ay + Amat[5]*az) / dn;
        float o2 = (Amat[6]*ax + Amat[7]*ay + Amat[8]*az) / dn;
        descT[dt_idx(ti, pi, 256 + 3*tid + 0)] = o0;
        descT[dt_idx(ti, pi, 256 + 3*tid + 1)] = o1;
        descT[dt_idx(ti, pi, 256 + 3*tid + 2)] = o2;
    }
}

// One layer: block = (type, 8-atom blk), thread = output neuron.
// K split into two independent accumulation streams for 2x loads in flight.
template<int K>
__global__ __launch_bounds__(256) void layer_kernel(
    const int* __restrict__ cnt,
    const float* __restrict__ actT,   // [2][NBLK][K][8]
    const float* __restrict__ W,      // [2][K][256]
    const float* __restrict__ B,      // [2][256]
    float* __restrict__ outT)         // [2][NBLK][256][8]
{
    constexpr int H = K / 2;
    const int t   = blockIdx.y;
    const int blk = blockIdx.x;
    const int o   = threadIdx.x;
    if (blk * 8 >= cnt[t]) return;

    const float* a = actT + ((size_t)t * NBLK + blk) * ((size_t)K * 8);
    const float* w = W + (size_t)t * K * 256 + o;

    float acc0[8], acc1[8];
    const float bias = B[t * 256 + o];
    #pragma unroll
    for (int q = 0; q < 8; ++q) { acc0[q] = bias; acc1[q] = 0.0f; }

    #pragma unroll 2
    for (int d = 0; d < H; ++d) {
        float w0 = w[(size_t)d * 256];
        float w1 = w[(size_t)(d + H) * 256];
        const float4* a40 = (const float4*)(a + (size_t)d * 8);
        const float4* a41 = (const float4*)(a + (size_t)(d + H) * 8);
        float4 x0 = a40[0], x1 = a40[1];
        float4 y0 = a41[0], y1 = a41[1];
        acc0[0] = fmaf(x0.x, w0, acc0[0]);
        acc0[1] = fmaf(x0.y, w0, acc0[1]);
        acc0[2] = fmaf(x0.z, w0, acc0[2]);
        acc0[3] = fmaf(x0.w, w0, acc0[3]);
        acc0[4] = fmaf(x1.x, w0, acc0[4]);
        acc0[5] = fmaf(x1.y, w0, acc0[5]);
        acc0[6] = fmaf(x1.z, w0, acc0[6]);
        acc0[7] = fmaf(x1.w, w0, acc0[7]);
        acc1[0] = fmaf(y0.x, w1, acc1[0]);
        acc1[1] = fmaf(y0.y, w1, acc1[1]);
        acc1[2] = fmaf(y0.z, w1, acc1[2]);
        acc1[3] = fmaf(y0.w, w1, acc1[3]);
        acc1[4] = fmaf(y1.x, w1, acc1[4]);
        acc1[5] = fmaf(y1.y, w1, acc1[5]);
        acc1[6] = fmaf(y1.z, w1, acc1[6]);
        acc1[7] = fmaf(y1.w, w1, acc1[7]);
    }

    float* op = outT + (((size_t)t * NBLK + blk) * 256 + o) * 8;
    #pragma unroll
    for (int q = 0; q < 8; ++q) op[q] = tanhf(acc0[q] + acc1[q]);
}

// Layer 3 + output layer + energy sum, fused. Same K-split structure.
__global__ __launch_bounds__(256) void layer3_energy_kernel(
    const int* __restrict__ cnt,
    const float* __restrict__ actT,   // h2T: [2][NBLK][256][8]
    const float* __restrict__ W,      // w3
    const float* __restrict__ B,      // b3
    const float* __restrict__ w4, const float* __restrict__ b4,
    float* __restrict__ out)
{
    __shared__ float red[256];
    constexpr int H = 128;
    const int t   = blockIdx.y;
    const int blk = blockIdx.x;
    const int o   = threadIdx.x;
    const int n   = cnt[t];
    if (blk * 8 >= n) return;
    const int nv = min(8, n - blk * 8);

    const float* a = actT + ((size_t)t * NBLK + blk) * (256 * 8);
    const float* w = W + (size_t)t * 256 * 256 + o;

    float acc0[8], acc1[8];
    const float bias = B[t * 256 + o];
    #pragma unroll
    for (int q = 0; q < 8; ++q) { acc0[q] = bias; acc1[q] = 0.0f; }

    #pragma unroll 2
    for (int d = 0; d < H; ++d) {
        float w0 = w[(size_t)d * 256];
        float w1 = w[(size_t)(d + H) * 256];
        const float4* a40 = (const float4*)(a + (size_t)d * 8);
        const float4* a41 = (const float4*)(a + (size_t)(d + H) * 8);
        float4 x0 = a40[0], x1 = a40[1];
        float4 y0 = a41[0], y1 = a41[1];
        acc0[0] = fmaf(x0.x, w0, acc0[0]);
        acc0[1] = fmaf(x0.y, w0, acc0[1]);
        acc0[2] = fmaf(x0.z, w0, acc0[2]);
        acc0[3] = fmaf(x0.w, w0, acc0[3]);
        acc0[4] = fmaf(x1.x, w0, acc0[4]);
        acc0[5] = fmaf(x1.y, w0, acc0[5]);
        acc0[6] = fmaf(x1.z, w0, acc0[6]);
        acc0[7] = fmaf(x1.w, w0, acc0[7]);
        acc1[0] = fmaf(y0.x, w1, acc1[0]);
        acc1[1] = fmaf(y0.y, w1, acc1[1]);
        acc1[2] = fmaf(y0.z, w1, acc1[2]);
        acc1[3] = fmaf(y0.w, w1, acc1[3]);
        acc1[4] = fmaf(y1.x, w1, acc1[4]);
        acc1[5] = fmaf(y1.y, w1, acc1[5]);
        acc1[6] = fmaf(y1.z, w1, acc1[6]);
        acc1[7] = fmaf(y1.w, w1, acc1[7]);
    }

    const float w4v = w4[t * 256 + o];
    float s = 0.0f;
    for (int q = 0; q < nv; ++q) s += tanhf(acc0[q] + acc1[q]) * w4v;
    red[o] = s;
    __syncthreads();
    for (int w2 = 128; w2 > 0; w2 >>= 1) {
        if (o < w2) red[o] += red[o + w2];
        __syncthreads();
    }
    if (o == 0) atomicAdd(out, red[0] + (float)nv * b4[t]);
}

extern "C" void kernel_launch(void* const* d_in, const int* in_sizes, int n_in,
                              void* d_out, int out_size, void* d_ws, size_t ws_size,
                              hipStream_t stream) {
    const float* xyz   = (const float*)d_in[0];
    const float* box   = (const float*)d_in[1];
    const int*   types = (const int*)  d_in[2];
    const float* w1 = (const float*)d_in[3];
    const float* b1 = (const float*)d_in[4];
    const float* w2 = (const float*)d_in[5];
    const float* b2 = (const float*)d_in[6];
    const float* w3 = (const float*)d_in[7];
    const float* b3 = (const float*)d_in[8];
    const float* w4 = (const float*)d_in[9];
    const float* b4 = (const float*)d_in[10];
    float* out = (float*)d_out;

    // workspace layout (4B units; packed kept 16B-aligned)
    float* p = (float*)d_ws;
    int*    cnt    = (int*)p;          p += 16;
    int*    pos    = (int*)p;          p += N_ATOMS;
    int*    lists  = (int*)p;          p += 2 * N_ATOMS;
    float4* packed = (float4*)p;       p += 2 * N_ATOMS * 4;
    float*  lfD    = p;                p += 4 * N_ATOMS;
    int*    lfJ    = (int*)p;          p += 4 * N_ATOMS;
    float*  aX     = p;                p += 96 * N_ATOMS;
    float*  aD     = p;                p += 32 * N_ATOMS;
    float*  descT  = p;                p += (size_t)2 * NBLK * D_DESC * 8;
    float*  h1T    = p;                p += (size_t)2 * NBLK * 256 * 8;
    float*  h2T    = p;                p += (size_t)2 * NBLK * 256 * 8;

    hipMemsetAsync(d_out, 0, sizeof(float), stream);
    hipMemsetAsync(d_ws, 0, 2 * sizeof(int), stream);

    build_lists_kernel<<<N_ATOMS / 256, 256, 0, stream>>>(types, cnt, lists, pos);
    pack_kernel<<<2 * N_ATOMS / 256, 256, 0, stream>>>(xyz, cnt, lists, packed);
    select_kernel<<<2 * N_ATOMS, 256, 0, stream>>>(xyz, box, cnt, packed, types, pos,
                                                   descT, aX, aD, lfD, lfJ);
    finalize_kernel<<<N_ATOMS, 64, 0, stream>>>(xyz, box, types, pos,
                                                aX, aD, lfD, lfJ, descT);
    dim3 g(NBLK, 2);
    layer_kernel<D_DESC><<<g, 256, 0, stream>>>(cnt, descT, w1, b1, h1T);
    layer_kernel<256><<<g, 256, 0, stream>>>(cnt, h1T, w2, b2, h2T);
    layer3_energy_kernel<<<g, 256, 0, stream>>>(cnt, h2T, w3, b3, w4, b4, out);
}

// Round 8
// 178.526 us; speedup vs baseline: 1.6266x; 1.1784x over previous
//
#include <hip/hip_runtime.h>

#define N_ATOMS 4096
#define D_DESC 352
#define NBLK 512   // 8-atom blocks per type
typedef unsigned long long ull;

// transposed descriptor/activation layout: [type][blk8][feature][q], q = p&7
__device__ __forceinline__ size_t dt_idx(int t, int p, int dd) {
    return (((size_t)t * NBLK + (p >> 3)) * D_DESC + dd) * 8 + (p & 7);
}

__device__ __forceinline__ float wrapr(float d, float box, float rbox) {
    return d - box * rintf(d * rbox);
}

__global__ __launch_bounds__(256) void build_lists_kernel(
    const int* __restrict__ types, int* __restrict__ cnt,
    int* __restrict__ lists, int* __restrict__ pos)
{
    int i = blockIdx.x * 256 + threadIdx.x;
    if (i < N_ATOMS) {
        int t = types[i];
        int p = atomicAdd(&cnt[t], 1);
        lists[t * N_ATOMS + p] = i;
        pos[i] = p;
    }
}

// packed[t][m] = (x, y, z, bits(j)) in list order -> coalesced select loads
__global__ __launch_bounds__(256) void pack_kernel(
    const float* __restrict__ xyz, const int* __restrict__ cnt,
    const int* __restrict__ lists, float4* __restrict__ packed)
{
    int idx = blockIdx.x * 256 + threadIdx.x;   // [0, 2*4096)
    int t = idx >> 12, m = idx & 4095;
    if (m < cnt[t]) {
        int j = lists[t * N_ATOMS + m];
        packed[idx] = make_float4(xyz[3*j+0], xyz[3*j+1], xyz[3*j+2],
                                  __uint_as_float((unsigned)j));
    }
}

// One block per (atom, type): threshold filter (count in [128,256]), then
// RANK-based exact placement on 43-bit keys (d2bits<<12 | j).
__global__ __launch_bounds__(256) void select_kernel(
    const float* __restrict__ xyz, const float* __restrict__ box,
    const int* __restrict__ cnt, const float4* __restrict__ packed,
    const int* __restrict__ types, const int* __restrict__ pos,
    float* __restrict__ descT, float* __restrict__ aX, float* __restrict__ aD,
    float* __restrict__ lfD, int* __restrict__ lfJ)
{
    __shared__ int part[2][4];
    __shared__ ull cand[512];
    __shared__ int cpos;

    const int i   = blockIdx.x >> 1;
    const int t   = blockIdx.x & 1;
    const int tid = threadIdx.x;
    const int n   = cnt[t];
    const float bx = box[0], by = box[1], bz = box[2];
    const float rbx = 1.0f/bx, rby = 1.0f/by, rbz = 1.0f/bz;
    const float xi = xyz[3*i+0], yi = xyz[3*i+1], zi = xyz[3*i+2];
    const unsigned ibits = (unsigned)i;
    const float4* pk = packed + t * N_ATOMS;

    // --- coalesced distance pass ---
    float d2r[16];
    #pragma unroll
    for (int c = 0; c < 16; ++c) {
        d2r[c] = __builtin_inff();
        int m = tid + (c << 8);
        if (m < n) {
            float4 p = pk[m];
            if (__float_as_uint(p.w) != ibits) {
                float dx = wrapr(xi - p.x, bx, rbx);
                float dy = wrapr(yi - p.y, by, rby);
                float dz = wrapr(zi - p.z, bz, rbz);
                d2r[c] = dx*dx + dy*dy + dz*dz;
            }
        }
    }

    if (tid == 0) cpos = 0;

    // --- threshold with count in [128, 256]; interpolated update ---
    float T = __powf(42.0f * bx * by * bz / (float)n, 0.6666667f);
    int tot = 0;
    for (int it = 0; it < 24; ++it) {
        int lc = 0;
        #pragma unroll
        for (int c = 0; c < 16; ++c) lc += (d2r[c] < T) ? 1 : 0;
        #pragma unroll
        for (int off = 32; off > 0; off >>= 1) lc += __shfl_xor(lc, off);
        if ((tid & 63) == 0) part[it & 1][tid >> 6] = lc;
        __syncthreads();
        tot = part[it & 1][0] + part[it & 1][1] + part[it & 1][2] + part[it & 1][3];
        if (tot >= 128 && tot <= 256) break;
        float f = __powf(176.0f / (float)max(tot, 1), 0.6666667f);
        T *= fminf(4.0f, fmaxf(0.25f, f));
    }

    // --- collect keys below T (exact superset of top-128) ---
    #pragma unroll
    for (int c = 0; c < 16; ++c) {
        if (d2r[c] < T) {
            int m = tid + (c << 8);
            unsigned j = __float_as_uint(pk[m].w);
            ull key = ((ull)__float_as_uint(d2r[c]) << 12) | j;
            int p = atomicAdd(&cpos, 1);
            if (p < 512) cand[p] = key;
        }
    }
    __syncthreads();
    const int count = min(cpos, 512);

    // --- rank-based placement: slot = #{keys < mykey}, exact sorted order ---
    const int ti = types[i];
    const int pi = pos[i];
    for (int m = tid; m < count; m += 256) {
        ull mykey = cand[m];
        int r = 0;
        #pragma unroll 4
        for (int k2 = 0; k2 < count; ++k2) r += (cand[k2] < mykey) ? 1 : 0;
        if (r < 128) {
            int j = (int)(mykey & 0xFFF);
            float d2 = __uint_as_float((unsigned)(mykey >> 12));
            float dist = sqrtf(d2);
            descT[dt_idx(ti, pi, t * 128 + r)] = 1.0f / (dist + 1e-16f);
            if (r < 16) {
                float dx = wrapr(xi - xyz[3*j+0], bx, rbx);
                float dy = wrapr(yi - xyz[3*j+1], by, rby);
                float dz = wrapr(zi - xyz[3*j+2], bz, rbz);
                int s = i * 32 + t * 16 + r;
                aX[3*s+0] = dx; aX[3*s+1] = dy; aX[3*s+2] = dz;
                aD[s] = dist;
            }
            if (r < 2) {
                lfD[i * 4 + t * 2 + r] = dist;
                lfJ[i * 4 + t * 2 + r] = j;
            }
        }
    }
}

// One block (64 threads) per atom: local frame + rotated angular features.
__global__ __launch_bounds__(64) void finalize_kernel(
    const float* __restrict__ xyz, const float* __restrict__ box,
    const int* __restrict__ types, const int* __restrict__ pos,
    const float* __restrict__ aX, const float* __restrict__ aD,
    const float* __restrict__ lfD, const int* __restrict__ lfJ,
    float* __restrict__ descT)
{
    __shared__ float Amat[9];
    const int i   = blockIdx.x;
    const int tid = threadIdx.x;

    if (tid == 0) {
        const float bx = box[0], by = box[1], bz = box[2];
        const float rbx = 1.0f/bx, rby = 1.0f/by, rbz = 1.0f/bz;
        const float xi = xyz[3*i+0], yi = xyz[3*i+1], zi = xyz[3*i+2];
        float cd[4]; int cj[4];
        #pragma unroll
        for (int c = 0; c < 4; ++c) { cd[c] = lfD[i*4+c]; cj[c] = lfJ[i*4+c]; }
        int i0 = 0; float b0 = cd[0];
        for (int c = 1; c < 4; ++c) if (cd[c] < b0) { b0 = cd[c]; i0 = c; }
        int i1 = -1; float b1v = 3.4e38f;
        for (int c = 0; c < 4; ++c) { if (c == i0) continue; if (cd[c] < b1v) { b1v = cd[c]; i1 = c; } }

        int ja = cj[i0], jb = cj[i1];
        float da = cd[i0], db = cd[i1];
        float r0x = wrapr(xi - xyz[3*ja+0], bx, rbx) / (da + 1e-16f);
        float r0y = wrapr(yi - xyz[3*ja+1], by, rby) / (da + 1e-16f);
        float r0z = wrapr(zi - xyz[3*ja+2], bz, rbz) / (da + 1e-16f);
        float r1x = wrapr(xi - xyz[3*jb+0], bx, rbx) / (db + 1e-16f);
        float r1y = wrapr(yi - xyz[3*jb+1], by, rby) / (db + 1e-16f);
        float r1z = wrapr(zi - xyz[3*jb+2], bz, rbz) / (db + 1e-16f);
        float dot = r0x*r1x + r0y*r1y + r0z*r1z;
        float v2x = r1x - dot*r0x, v2y = r1y - dot*r0y, v2z = r1z - dot*r0z;
        float n2 = sqrtf(v2x*v2x + v2y*v2y + v2z*v2z);
        v2x /= n2; v2y /= n2; v2z /= n2;
        float v3x = r0y*r1z - r0z*r1y;
        float v3y = r0z*r1x - r0x*r1z;
        float v3z = r0x*r1y - r0y*r1x;
        float n3 = sqrtf(v3x*v3x + v3y*v3y + v3z*v3z);
        v3x /= n3; v3y /= n3; v3z /= n3;
        Amat[0]=r0x; Amat[1]=r0y; Amat[2]=r0z;
        Amat[3]=v2x; Amat[4]=v2y; Amat[5]=v2z;
        Amat[6]=v3x; Amat[7]=v3y; Amat[8]=v3z;
    }
    __syncthreads();

    if (tid < 32) {
        const int ti = types[i];
        const int pi = pos[i];
        int s = i * 32 + tid;
        float d  = aD[s];
        float dn = d + 1e-16f;
        float ax = aX[3*s+0] / dn;
        float ay = aX[3*s+1] / dn;
        float az = aX[3*s+2] / dn;
        float o0 = (Amat[0]*ax + Amat[1]*ay + Amat[2]*az) / dn;
        float o1 = (Amat[3]*ax + Amat[4]*ay + Amat[5]*az) / dn;
        float o2 = (Amat[6]*ax + Amat[7]*ay + Amat[8]*az) / dn;
        descT[dt_idx(ti, pi, 256 + 3*tid + 0)] = o0;
        descT[dt_idx(ti, pi, 256 + 3*tid + 1)] = o1;
        descT[dt_idx(ti, pi, 256 + 3*tid + 2)] = o2;
    }
}

// Layer: block = (type, 8-atom blk, neuron-half). 256 threads =
// 128 neurons x 2 K-halves. Acts staged in LDS; partials combined via LDS.
// Grid 2048 blocks -> 8 blocks/CU -> full wave occupancy.
template<int K>
__global__ __launch_bounds__(256) void layer_kernel(
    const int* __restrict__ cnt,
    const float* __restrict__ actT,   // [2][NBLK][K][8]
    const float* __restrict__ W,      // [2][K][256]
    const float* __restrict__ B,      // [2][256]
    float* __restrict__ outT)         // [2][NBLK][256][8]
{
    constexpr int H = K / 2;
    __shared__ float sa[K * 8];
    __shared__ float ps[128 * 9];     // padded partial-sum buffer

    const int t   = blockIdx.y;
    const int blk = blockIdx.x >> 1;
    const int nb  = (blockIdx.x & 1) * 128;
    if (blk * 8 >= cnt[t]) return;
    const int tid = threadIdx.x;
    const int kh  = tid >> 7;         // K-half
    const int ln  = tid & 127;        // local neuron
    const int o   = nb + ln;

    const float* a = actT + ((size_t)t * NBLK + blk) * ((size_t)K * 8);
    for (int idx = tid; idx < K * 2; idx += 256)
        ((float4*)sa)[idx] = ((const float4*)a)[idx];
    __syncthreads();

    const float* w = W + (size_t)t * K * 256 + (size_t)kh * H * 256 + o;
    const float* s = sa + kh * H * 8;

    float acc[8];
    #pragma unroll
    for (int q = 0; q < 8; ++q) acc[q] = 0.0f;

    #pragma unroll 4
    for (int d = 0; d < H; ++d) {
        float wv = w[(size_t)d * 256];
        const float4* sp = (const float4*)(s + d * 8);
        float4 x0 = sp[0], x1 = sp[1];
        acc[0] = fmaf(x0.x, wv, acc[0]);
        acc[1] = fmaf(x0.y, wv, acc[1]);
        acc[2] = fmaf(x0.z, wv, acc[2]);
        acc[3] = fmaf(x0.w, wv, acc[3]);
        acc[4] = fmaf(x1.x, wv, acc[4]);
        acc[5] = fmaf(x1.y, wv, acc[5]);
        acc[6] = fmaf(x1.z, wv, acc[6]);
        acc[7] = fmaf(x1.w, wv, acc[7]);
    }

    if (kh) {
        #pragma unroll
        for (int q = 0; q < 8; ++q) ps[ln * 9 + q] = acc[q];
    }
    __syncthreads();
    if (!kh) {
        const float bias = B[t * 256 + o];
        float* op = outT + (((size_t)t * NBLK + blk) * 256 + o) * 8;
        #pragma unroll
        for (int q = 0; q < 8; ++q)
            op[q] = tanhf(acc[q] + ps[ln * 9 + q] + bias);
    }
}

// Layer 3 + output layer + energy sum, fused; same split structure.
__global__ __launch_bounds__(256) void layer3_energy_kernel(
    const int* __restrict__ cnt,
    const float* __restrict__ actT,   // h2T: [2][NBLK][256][8]
    const float* __restrict__ W,      // w3
    const float* __restrict__ B,      // b3
    const float* __restrict__ w4, const float* __restrict__ b4,
    float* __restrict__ out)
{
    constexpr int K = 256, H = 128;
    __shared__ float sa[K * 8];
    __shared__ float ps[128 * 9];
    __shared__ float red[256];

    const int t   = blockIdx.y;
    const int blk = blockIdx.x >> 1;
    const int nb  = (blockIdx.x & 1) * 128;
    const int n   = cnt[t];
    if (blk * 8 >= n) return;
    const int nv  = min(8, n - blk * 8);
    const int tid = threadIdx.x;
    const int kh  = tid >> 7;
    const int ln  = tid & 127;
    const int o   = nb + ln;

    const float* a = actT + ((size_t)t * NBLK + blk) * ((size_t)K * 8);
    for (int idx = tid; idx < K * 2; idx += 256)
        ((float4*)sa)[idx] = ((const float4*)a)[idx];
    __syncthreads();

    const float* w = W + (size_t)t * K * 256 + (size_t)kh * H * 256 + o;
    const float* s = sa + kh * H * 8;

    float acc[8];
    #pragma unroll
    for (int q = 0; q < 8; ++q) acc[q] = 0.0f;

    #pragma unroll 4
    for (int d = 0; d < H; ++d) {
        float wv = w[(size_t)d * 256];
        const float4* sp = (const float4*)(s + d * 8);
        float4 x0 = sp[0], x1 = sp[1];
        acc[0] = fmaf(x0.x, wv, acc[0]);
        acc[1] = fmaf(x0.y, wv, acc[1]);
        acc[2] = fmaf(x0.z, wv, acc[2]);
        acc[3] = fmaf(x0.w, wv, acc[3]);
        acc[4] = fmaf(x1.x, wv, acc[4]);
        acc[5] = fmaf(x1.y, wv, acc[5]);
        acc[6] = fmaf(x1.z, wv, acc[6]);
        acc[7] = fmaf(x1.w, wv, acc[7]);
    }

    if (kh) {
        #pragma unroll
        for (int q = 0; q < 8; ++q) ps[ln * 9 + q] = acc[q];
    }
    __syncthreads();

    float ss = 0.0f;
    if (!kh) {
        const float bias = B[t * 256 + o];
        const float w4v  = w4[t * 256 + o];
        for (int q = 0; q < nv; ++q)
            ss += tanhf(acc[q] + ps[ln * 9 + q] + bias);
        ss *= w4v;
    }
    red[tid] = ss;
    __syncthreads();
    for (int w2 = 128; w2 > 0; w2 >>= 1) {
        if (tid < w2) red[tid] += red[tid + w2];
        __syncthreads();
    }
    if (tid == 0)
        atomicAdd(out, red[0] + ((nb == 0) ? (float)nv * b4[t] : 0.0f));
}

extern "C" void kernel_launch(void* const* d_in, const int* in_sizes, int n_in,
                              void* d_out, int out_size, void* d_ws, size_t ws_size,
                              hipStream_t stream) {
    const float* xyz   = (const float*)d_in[0];
    const float* box   = (const float*)d_in[1];
    const int*   types = (const int*)  d_in[2];
    const float* w1 = (const float*)d_in[3];
    const float* b1 = (const float*)d_in[4];
    const float* w2 = (const float*)d_in[5];
    const float* b2 = (const float*)d_in[6];
    const float* w3 = (const float*)d_in[7];
    const float* b3 = (const float*)d_in[8];
    const float* w4 = (const float*)d_in[9];
    const float* b4 = (const float*)d_in[10];
    float* out = (float*)d_out;

    // workspace layout (4B units; packed kept 16B-aligned)
    float* p = (float*)d_ws;
    int*    cnt    = (int*)p;          p += 16;
    int*    pos    = (int*)p;          p += N_ATOMS;
    int*    lists  = (int*)p;          p += 2 * N_ATOMS;
    float4* packed = (float4*)p;       p += 2 * N_ATOMS * 4;
    float*  lfD    = p;                p += 4 * N_ATOMS;
    int*    lfJ    = (int*)p;          p += 4 * N_ATOMS;
    float*  aX     = p;                p += 96 * N_ATOMS;
    float*  aD     = p;                p += 32 * N_ATOMS;
    float*  descT  = p;                p += (size_t)2 * NBLK * D_DESC * 8;
    float*  h1T    = p;                p += (size_t)2 * NBLK * 256 * 8;
    float*  h2T    = p;                p += (size_t)2 * NBLK * 256 * 8;

    hipMemsetAsync(d_out, 0, sizeof(float), stream);
    hipMemsetAsync(d_ws, 0, 2 * sizeof(int), stream);

    build_lists_kernel<<<N_ATOMS / 256, 256, 0, stream>>>(types, cnt, lists, pos);
    pack_kernel<<<2 * N_ATOMS / 256, 256, 0, stream>>>(xyz, cnt, lists, packed);
    select_kernel<<<2 * N_ATOMS, 256, 0, stream>>>(xyz, box, cnt, packed, types, pos,
                                                   descT, aX, aD, lfD, lfJ);
    finalize_kernel<<<N_ATOMS, 64, 0, stream>>>(xyz, box, types, pos,
                                                aX, aD, lfD, lfJ, descT);
    dim3 g(NBLK * 2, 2);
    layer_kernel<D_DESC><<<g, 256, 0, stream>>>(cnt, descT, w1, b1, h1T);
    layer_kernel<256><<<g, 256, 0, stream>>>(cnt, h1T, w2, b2, h2T);
    layer3_energy_kernel<<<g, 256, 0, stream>>>(cnt, h2T, w3, b3, w4, b4, out);
}